// Round 1
// baseline (526.325 us; speedup 1.0000x reference)
//
#include <hip/hip_runtime.h>

#define BN    32768   // B*N = 512*64
#define KNB   12      // neighbors
#define DIM   128

// ---------------------------------------------------------------------------
// Kernel A: per (b,n) node -> attention logits, softmax over K, weighted
// neighbor aggregation.  Block = 128 threads = 2 waves; each wave handles one
// (b,n) pair independently.  Each lane owns output dims d and d+64, so every
// LDS read of the neighbor tile is reused for 2 accumulator columns.
// ---------------------------------------------------------------------------
__global__ __launch_bounds__(128) void attn_agg_kernel(
    const float* __restrict__ neighbor,  // [BN, 12, 128]
    const float* __restrict__ nw,        // [BN, 12]
    const float* __restrict__ extra,     // [BN, 128]
    const float* __restrict__ w1,        // [129, 128]
    const float* __restrict__ w2,        // [128]
    float* __restrict__ agg)             // [BN, 128]
{
    __shared__ float nbr_lds[2][KNB * DIM];  // 2 x 6 KB
    __shared__ float ext_lds[2][DIM];

    const int wave = threadIdx.x >> 6;
    const int lane = threadIdx.x & 63;
    const int bn   = blockIdx.x * 2 + wave;

    const float* nbr_g = neighbor + (size_t)bn * (KNB * DIM);
    const float* ext_g = extra    + (size_t)bn * DIM;

    // Stage neighbor tile (1536 floats) + extra (128 floats) via float4.
    {
        const float4* s  = (const float4*)nbr_g;
        float4*       d4 = (float4*)nbr_lds[wave];
        #pragma unroll
        for (int j = 0; j < 6; ++j) d4[lane + j * 64] = s[lane + j * 64];
        if (lane < 32)
            ((float4*)ext_lds[wave])[lane] = ((const float4*)ext_g)[lane];
    }
    __syncthreads();

    const int d0 = lane;
    const int d1 = lane + 64;

    float acc0[KNB], acc1[KNB];
    #pragma unroll
    for (int k = 0; k < KNB; ++k) { acc0[k] = 0.f; acc1[k] = 0.f; }

    const float* nbr_s = nbr_lds[wave];
    const float* ext_s = ext_lds[wave];

    // alpha[k][d] = sum_f (extra[f]*nbr[k][f]) * w1[f][d]
    //            = sum_f nbr[k][f] * (extra[f]*w1[f][d])
    for (int f = 0; f < DIM; f += 4) {
        float4 ev = *(const float4*)(ext_s + f);
        float w1a[4], w1b[4];
        #pragma unroll
        for (int j = 0; j < 4; ++j) {
            w1a[j] = w1[(f + j) * DIM + d0];
            w1b[j] = w1[(f + j) * DIM + d1];
        }
        const float q0[4] = { ev.x * w1a[0], ev.y * w1a[1], ev.z * w1a[2], ev.w * w1a[3] };
        const float q1[4] = { ev.x * w1b[0], ev.y * w1b[1], ev.z * w1b[2], ev.w * w1b[3] };
        #pragma unroll
        for (int k = 0; k < KNB; ++k) {
            float4 nv = *(const float4*)(nbr_s + k * DIM + f);
            acc0[k] += nv.x * q0[0] + nv.y * q0[1] + nv.z * q0[2] + nv.w * q0[3];
            acc1[k] += nv.x * q1[0] + nv.y * q1[1] + nv.z * q1[2] + nv.w * q1[3];
        }
    }

    // f = 128 row of w1: edge-weight feature, then leaky_relu and dot with w2.
    const float* nwp = nw + (size_t)bn * KNB;
    const float w1t0 = w1[DIM * DIM + d0];
    const float w1t1 = w1[DIM * DIM + d1];
    const float w2a  = w2[d0];
    const float w2b  = w2[d1];

    float part[KNB];
    #pragma unroll
    for (int k = 0; k < KNB; ++k) {
        const float nwk = nwp[k];
        float a0 = acc0[k] + nwk * w1t0;
        float a1 = acc1[k] + nwk * w1t1;
        a0 = a0 > 0.f ? a0 : 0.2f * a0;   // leaky_relu(0.2)
        a1 = a1 > 0.f ? a1 : 0.2f * a1;
        part[k] = a0 * w2a + a1 * w2b;
    }

    // Wave-level reduction of the 12 logits (64 lanes -> scalar each).
    #pragma unroll
    for (int k = 0; k < KNB; ++k) {
        float v = part[k];
        #pragma unroll
        for (int off = 32; off > 0; off >>= 1) v += __shfl_xor(v, off, 64);
        part[k] = v;
    }

    // Softmax over K=12, redundantly in every lane (cheap).
    float m = part[0];
    #pragma unroll
    for (int k = 1; k < KNB; ++k) m = fmaxf(m, part[k]);
    float s = 0.f;
    #pragma unroll
    for (int k = 0; k < KNB; ++k) { part[k] = expf(part[k] - m); s += part[k]; }
    const float inv = 1.f / s;

    // agg[d] = sum_k alpha[k] * nbr[k][d]
    float a0 = 0.f, a1 = 0.f;
    #pragma unroll
    for (int k = 0; k < KNB; ++k) {
        const float aw = part[k] * inv;
        a0 += aw * nbr_s[k * DIM + d0];
        a1 += aw * nbr_s[k * DIM + d1];
    }
    agg[(size_t)bn * DIM + d0] = a0;
    agg[(size_t)bn * DIM + d1] = a1;
}

// ---------------------------------------------------------------------------
// Kernel B: out = relu([self || agg] @ w3).  64-row tile in LDS (exactly
// 64 KB), each thread computes 16 rows x 2 columns so each LDS b128 read
// feeds 8 FMAs x 2 columns.  In-place safe w.r.t. agg==out: the full tile is
// loaded into LDS (and __syncthreads) before any store of the same rows.
// ---------------------------------------------------------------------------
__global__ __launch_bounds__(256) void out_gemm_kernel(
    const float* __restrict__ selfv,  // [BN, 128]
    const float* __restrict__ agg,    // [BN, 128]
    const float* __restrict__ w3,     // [256, 128]
    float* __restrict__ out)          // [BN, 128]
{
    __shared__ float in_lds[64][256];  // 64 KB: [row][0:128]=self, [128:256]=agg

    const int row0 = blockIdx.x * 64;
    const int tid  = threadIdx.x;

    // Stage 64 rows x 256 feats as float4 (4096 vec4, 16 per thread).
    for (int idx = tid; idx < 64 * 64; idx += 256) {
        const int r  = idx >> 6;          // row within tile
        const int c4 = idx & 63;          // float4 column
        float4 v;
        if (c4 < 32) v = ((const float4*)(selfv + (size_t)(row0 + r) * DIM))[c4];
        else         v = ((const float4*)(agg   + (size_t)(row0 + r) * DIM))[c4 - 32];
        ((float4*)in_lds[r])[c4] = v;
    }
    __syncthreads();

    const int d0   = tid & 63;        // column pair d0, d0+64
    const int rgrp = tid >> 6;        // 4 groups of 16 rows
    const int rbase = rgrp * 16;

    float acc0[16], acc1[16];
    #pragma unroll
    for (int r = 0; r < 16; ++r) { acc0[r] = 0.f; acc1[r] = 0.f; }

    for (int f = 0; f < 256; f += 4) {
        float w3a[4], w3b[4];
        #pragma unroll
        for (int j = 0; j < 4; ++j) {
            w3a[j] = w3[(f + j) * DIM + d0];
            w3b[j] = w3[(f + j) * DIM + d0 + 64];
        }
        #pragma unroll
        for (int r = 0; r < 16; ++r) {
            float4 iv = *(const float4*)(&in_lds[rbase + r][f]);
            acc0[r] += iv.x * w3a[0] + iv.y * w3a[1] + iv.z * w3a[2] + iv.w * w3a[3];
            acc1[r] += iv.x * w3b[0] + iv.y * w3b[1] + iv.z * w3b[2] + iv.w * w3b[3];
        }
    }

    #pragma unroll
    for (int r = 0; r < 16; ++r) {
        const size_t row = (size_t)(row0 + rbase + r);
        out[row * DIM + d0]      = fmaxf(acc0[r], 0.f);
        out[row * DIM + d0 + 64] = fmaxf(acc1[r], 0.f);
    }
}

// ---------------------------------------------------------------------------
extern "C" void kernel_launch(void* const* d_in, const int* in_sizes, int n_in,
                              void* d_out, int out_size, void* d_ws, size_t ws_size,
                              hipStream_t stream) {
    const float* selfv    = (const float*)d_in[0];  // [B,N,128]
    const float* neighbor = (const float*)d_in[1];  // [B,N,12,128]
    // d_in[2] = batch_size (scalar), d_in[3] = masks (unused by reference)
    const float* nw       = (const float*)d_in[4];  // [B,N,12]
    const float* extra    = (const float*)d_in[5];  // [B,N,128]
    const float* w1       = (const float*)d_in[6];  // [129,128]
    const float* w2       = (const float*)d_in[7];  // [128,1]
    const float* w3       = (const float*)d_in[8];  // [256,128]
    float* out = (float*)d_out;

    const size_t agg_bytes = (size_t)BN * DIM * sizeof(float);
    float* aggbuf = (ws_size >= agg_bytes) ? (float*)d_ws : out;  // in-place fallback is safe

    attn_agg_kernel<<<BN / 2, 128, 0, stream>>>(neighbor, nw, extra, w1, w2, aggbuf);
    out_gemm_kernel<<<BN / 64, 256, 0, stream>>>(selfv, aggbuf, w3, out);
}

// Round 2
// 345.918 us; speedup vs baseline: 1.5215x; 1.5215x over previous
//
#include <hip/hip_runtime.h>

#define BN    32768   // B*N
#define KNB   12
#define DIM   128

typedef __attribute__((ext_vector_type(8))) short bf16x8;
typedef __attribute__((ext_vector_type(4))) float f32x4;

__device__ inline unsigned short f2b(float x) {
    union { float f; unsigned u; } v; v.f = x;
    unsigned r = v.u + 0x7fffu + ((v.u >> 16) & 1u);   // RNE
    return (unsigned short)(r >> 16);
}
__device__ inline float b2f(unsigned short s) {
    union { unsigned u; float f; } v; v.u = ((unsigned)s) << 16; return v.f;
}
__device__ inline unsigned pack2(float a, float b) {
    return (unsigned)f2b(a) | ((unsigned)f2b(b) << 16);
}

// ---------------------------------------------------------------------------
// Prep: w1 (128x128 part) and w3 (256x128) -> bf16 in MFMA B-fragment order.
// Fragment fi, lane, j  ->  element B[k = ks*32 + (lane>>4)*8 + j][n = nt*16 + (lane&15)]
// w1f: fi = nt*4 + ks  (nt 0..7, ks 0..3)   16384 elems
// w3f: fi = nt*8 + ks  (nt 0..7, ks 0..7)   32768 elems
// ---------------------------------------------------------------------------
__global__ void prep_kernel(const float* __restrict__ w1, const float* __restrict__ w3,
                            unsigned short* __restrict__ w1f, unsigned short* __restrict__ w3f) {
    int idx = blockIdx.x * 256 + threadIdx.x;
    if (idx < 16384) {
        int j = idx & 7, lane = (idx >> 3) & 63, fi = idx >> 9;
        int nt = fi >> 2, ks = fi & 3;
        int k = ks * 32 + (lane >> 4) * 8 + j;
        int n = nt * 16 + (lane & 15);
        w1f[idx] = f2b(w1[k * DIM + n]);
    }
    if (idx < 32768) {
        int j = idx & 7, lane = (idx >> 3) & 63, fi = idx >> 9;
        int nt = fi >> 3, ks = fi & 7;
        int k = ks * 32 + (lane >> 4) * 8 + j;
        int n = nt * 16 + (lane & 15);
        w3f[idx] = f2b(w3[k * DIM + n]);
    }
}

// ---------------------------------------------------------------------------
// Kernel 1: per block = 8 nodes (M = 96 rows of (node,k)).
// GEMM1: alpha[96,128] = feat[96,128]@w1 via 16x16x32 bf16 MFMA, epilogue adds
// nw rank-1 term, leaky_relu, dot w2 -> logits; softmax over K; agg from LDS
// neighbor copy; agg written as bf16.
// ---------------------------------------------------------------------------
#define T1   8
#define M1   96
#define LDA1 136    // bf16 leading dim: 128 + 8 pad (stride 68 words -> 2-way, free)

__global__ __launch_bounds__(256) void attn_mfma_kernel(
    const float* __restrict__ nbr_g,   // [BN,12,128]
    const float* __restrict__ nw_g,    // [BN,12]
    const float* __restrict__ ext_g,   // [BN,128]
    const float* __restrict__ w1,      // [129,128] fp32 (row 128 used here)
    const float* __restrict__ w2,      // [128]
    const unsigned short* __restrict__ w1f,
    unsigned short* __restrict__ aggb) // [BN,128] bf16
{
    __shared__ unsigned short featb[M1 * LDA1];
    __shared__ unsigned short nbrb[M1 * LDA1];
    __shared__ float logits[M1];
    __shared__ float wts[M1];

    const int tid  = threadIdx.x;
    const int lane = tid & 63;
    const int wv   = tid >> 6;
    const int bn0  = blockIdx.x * T1;

    // ---- stage neighbor (3072 float4) -> bf16 nbr + bf16 feat in LDS ----
    const float4* nsrc  = (const float4*)(nbr_g + (size_t)bn0 * KNB * DIM);
    const float*  ebase = ext_g + (size_t)bn0 * DIM;
    #pragma unroll
    for (int i = 0; i < 12; ++i) {
        int f4  = tid + i * 256;          // 0..3071
        int row = f4 >> 5;                // 32 float4 per row
        int c4  = f4 & 31;
        int node = row / 12;
        float4 nv = nsrc[f4];
        float4 ev = *(const float4*)(ebase + node * DIM + c4 * 4);
        uint2 pn; pn.x = pack2(nv.x, nv.y);           pn.y = pack2(nv.z, nv.w);
        uint2 pf; pf.x = pack2(nv.x * ev.x, nv.y * ev.y); pf.y = pack2(nv.z * ev.z, nv.w * ev.w);
        *(uint2*)&nbrb [row * LDA1 + c4 * 4] = pn;
        *(uint2*)&featb[row * LDA1 + c4 * 4] = pf;
    }
    __syncthreads();

    // ---- per-wave constants: B fragments (w1), w2 / w1-last-row per n-tile ----
    bf16x8 Bf[32];
    {
        const bf16x8* w1fv = (const bf16x8*)w1f;
        #pragma unroll
        for (int i = 0; i < 32; ++i) Bf[i] = w1fv[i * 64 + lane];
    }
    const int m    = lane & 15;
    const int quad = lane >> 4;
    float w2v[8], w1l[8];
    #pragma unroll
    for (int nt = 0; nt < 8; ++nt) {
        w2v[nt] = w2[nt * 16 + m];
        w1l[nt] = w1[DIM * DIM + nt * 16 + m];
    }

    // ---- GEMM1 + logits: 6 M-tiles over 4 waves ----
    for (int mt = wv; mt < 6; mt += 4) {
        const int rowbase = mt * 16 + quad * 4;
        float nwv[4];
        #pragma unroll
        for (int r = 0; r < 4; ++r) nwv[r] = nw_g[(size_t)bn0 * KNB + rowbase + r];
        float lp[4] = {0.f, 0.f, 0.f, 0.f};
        #pragma unroll
        for (int nt = 0; nt < 8; ++nt) {
            f32x4 acc = {0.f, 0.f, 0.f, 0.f};
            #pragma unroll
            for (int ks = 0; ks < 4; ++ks) {
                bf16x8 af = *(const bf16x8*)&featb[(mt * 16 + m) * LDA1 + ks * 32 + quad * 8];
                acc = __builtin_amdgcn_mfma_f32_16x16x32_bf16(af, Bf[nt * 4 + ks], acc, 0, 0, 0);
            }
            #pragma unroll
            for (int r = 0; r < 4; ++r) {
                float v = acc[r] + nwv[r] * w1l[nt];   // 129th feature (edge weight)
                v = v > 0.f ? v : 0.2f * v;            // leaky_relu(0.2)
                lp[r] += v * w2v[nt];
            }
        }
        #pragma unroll
        for (int r = 0; r < 4; ++r) {
            float v = lp[r];
            v += __shfl_xor(v, 1, 64); v += __shfl_xor(v, 2, 64);
            v += __shfl_xor(v, 4, 64); v += __shfl_xor(v, 8, 64);
            if (m == 0) logits[rowbase + r] = v;
        }
    }
    __syncthreads();

    // ---- softmax over K=12, one thread per node ----
    if (tid < T1) {
        float mx = logits[tid * KNB];
        #pragma unroll
        for (int k = 1; k < KNB; ++k) mx = fmaxf(mx, logits[tid * KNB + k]);
        float s = 0.f; float e[KNB];
        #pragma unroll
        for (int k = 0; k < KNB; ++k) { e[k] = __expf(logits[tid * KNB + k] - mx); s += e[k]; }
        float inv = 1.f / s;
        #pragma unroll
        for (int k = 0; k < KNB; ++k) wts[tid * KNB + k] = e[k] * inv;
    }
    __syncthreads();

    // ---- agg: node = tid>>5, 4 dims per thread, neighbor from LDS ----
    {
        const int node = tid >> 5;
        const int dd   = (tid & 31) * 4;
        float a0 = 0.f, a1 = 0.f, a2 = 0.f, a3 = 0.f;
        #pragma unroll
        for (int k = 0; k < KNB; ++k) {
            float w = wts[node * KNB + k];
            uint2 pk = *(const uint2*)&nbrb[(node * KNB + k) * LDA1 + dd];
            a0 += w * b2f((unsigned short)(pk.x & 0xffff));
            a1 += w * b2f((unsigned short)(pk.x >> 16));
            a2 += w * b2f((unsigned short)(pk.y & 0xffff));
            a3 += w * b2f((unsigned short)(pk.y >> 16));
        }
        uint2 po; po.x = pack2(a0, a1); po.y = pack2(a2, a3);
        *(uint2*)&aggb[(size_t)(bn0 + node) * DIM + dd] = po;
    }
}

// ---------------------------------------------------------------------------
// Kernel 2: out = relu([self || agg] @ w3).  64 rows/block, A bf16 in LDS,
// w3 fragments (2 n-tiles per wave) in registers.
// ---------------------------------------------------------------------------
#define LDA2 264    // bf16 leading dim: 256 + 8 pad

__global__ __launch_bounds__(256) void out_mfma_kernel(
    const float* __restrict__ selfv,          // [BN,128]
    const unsigned short* __restrict__ aggb,  // [BN,128] bf16
    const unsigned short* __restrict__ w3f,
    float* __restrict__ out)                  // [BN,128]
{
    __shared__ unsigned short A[64 * LDA2];

    const int tid  = threadIdx.x;
    const int lane = tid & 63;
    const int wv   = tid >> 6;
    const int row0 = blockIdx.x * 64;

    // stage self fp32 -> bf16 (cols 0..127)
    const float4* ssrc = (const float4*)(selfv + (size_t)row0 * DIM);
    #pragma unroll
    for (int i = 0; i < 8; ++i) {
        int f4 = tid + i * 256;   // 0..2047
        int r  = f4 >> 5, c4 = f4 & 31;
        float4 v = ssrc[f4];
        uint2 p; p.x = pack2(v.x, v.y); p.y = pack2(v.z, v.w);
        *(uint2*)&A[r * LDA2 + c4 * 4] = p;
    }
    // stage agg bf16 (cols 128..255)
    const bf16x8* asrc = (const bf16x8*)(aggb + (size_t)row0 * DIM);
    #pragma unroll
    for (int i = 0; i < 4; ++i) {
        int idx = tid + i * 256;  // 0..1023, 8 shorts each
        int r = idx >> 4, c8 = idx & 15;
        *(bf16x8*)&A[r * LDA2 + 128 + c8 * 8] = asrc[idx];
    }
    __syncthreads();

    // B fragments: this wave owns n-tiles 2*wv, 2*wv+1  (16 frags)
    bf16x8 Bf[16];
    {
        const bf16x8* w3fv = (const bf16x8*)w3f;
        #pragma unroll
        for (int i = 0; i < 16; ++i) {
            int nt = wv * 2 + (i >> 3), ks = i & 7;
            Bf[i] = w3fv[(nt * 8 + ks) * 64 + lane];
        }
    }
    const int m = lane & 15, quad = lane >> 4;

    for (int mt = 0; mt < 4; ++mt) {
        f32x4 acc0 = {0.f, 0.f, 0.f, 0.f}, acc1 = {0.f, 0.f, 0.f, 0.f};
        #pragma unroll
        for (int ks = 0; ks < 8; ++ks) {
            bf16x8 af = *(const bf16x8*)&A[(mt * 16 + m) * LDA2 + ks * 32 + quad * 8];
            acc0 = __builtin_amdgcn_mfma_f32_16x16x32_bf16(af, Bf[ks],     acc0, 0, 0, 0);
            acc1 = __builtin_amdgcn_mfma_f32_16x16x32_bf16(af, Bf[8 + ks], acc1, 0, 0, 0);
        }
        #pragma unroll
        for (int r = 0; r < 4; ++r) {
            int row = row0 + mt * 16 + quad * 4 + r;
            out[(size_t)row * DIM + wv * 32 + m]      = fmaxf(acc0[r], 0.f);
            out[(size_t)row * DIM + wv * 32 + 16 + m] = fmaxf(acc1[r], 0.f);
        }
    }
}

// ===========================================================================
// Fallback fp32 path (round-1 kernels) if ws is too small for the bf16 plan.
// ===========================================================================
__global__ __launch_bounds__(128) void attn_agg_fb(
    const float* __restrict__ neighbor, const float* __restrict__ nw,
    const float* __restrict__ extra, const float* __restrict__ w1,
    const float* __restrict__ w2, float* __restrict__ agg)
{
    __shared__ float nbr_lds[2][KNB * DIM];
    const int wave = threadIdx.x >> 6, lane = threadIdx.x & 63;
    const int bn = blockIdx.x * 2 + wave;
    const float* nbr_gp = neighbor + (size_t)bn * (KNB * DIM);
    const float* ext_gp = extra + (size_t)bn * DIM;
    {
        const float4* s = (const float4*)nbr_gp;
        float4* d4 = (float4*)nbr_lds[wave];
        #pragma unroll
        for (int j = 0; j < 6; ++j) d4[lane + j * 64] = s[lane + j * 64];
    }
    __syncthreads();
    const int d0 = lane, d1 = lane + 64;
    float acc0[KNB], acc1[KNB];
    #pragma unroll
    for (int k = 0; k < KNB; ++k) { acc0[k] = 0.f; acc1[k] = 0.f; }
    const float* nbr_s = nbr_lds[wave];
    for (int f = 0; f < DIM; f += 4) {
        float4 ev = *(const float4*)(ext_gp + f);
        float q0[4], q1[4];
        #pragma unroll
        for (int j = 0; j < 4; ++j) {
            q0[j] = ((const float*)&ev)[j] * w1[(f + j) * DIM + d0];
            q1[j] = ((const float*)&ev)[j] * w1[(f + j) * DIM + d1];
        }
        #pragma unroll
        for (int k = 0; k < KNB; ++k) {
            float4 nv = *(const float4*)(nbr_s + k * DIM + f);
            acc0[k] += nv.x * q0[0] + nv.y * q0[1] + nv.z * q0[2] + nv.w * q0[3];
            acc1[k] += nv.x * q1[0] + nv.y * q1[1] + nv.z * q1[2] + nv.w * q1[3];
        }
    }
    const float* nwp = nw + (size_t)bn * KNB;
    const float w1t0 = w1[DIM * DIM + d0], w1t1 = w1[DIM * DIM + d1];
    const float w2a = w2[d0], w2b = w2[d1];
    float part[KNB];
    #pragma unroll
    for (int k = 0; k < KNB; ++k) {
        float a0 = acc0[k] + nwp[k] * w1t0, a1 = acc1[k] + nwp[k] * w1t1;
        a0 = a0 > 0.f ? a0 : 0.2f * a0; a1 = a1 > 0.f ? a1 : 0.2f * a1;
        part[k] = a0 * w2a + a1 * w2b;
    }
    #pragma unroll
    for (int k = 0; k < KNB; ++k) {
        float v = part[k];
        #pragma unroll
        for (int off = 32; off > 0; off >>= 1) v += __shfl_xor(v, off, 64);
        part[k] = v;
    }
    float mx = part[0];
    #pragma unroll
    for (int k = 1; k < KNB; ++k) mx = fmaxf(mx, part[k]);
    float s = 0.f;
    #pragma unroll
    for (int k = 0; k < KNB; ++k) { part[k] = __expf(part[k] - mx); s += part[k]; }
    const float inv = 1.f / s;
    float a0 = 0.f, a1 = 0.f;
    #pragma unroll
    for (int k = 0; k < KNB; ++k) {
        const float aw = part[k] * inv;
        a0 += aw * nbr_s[k * DIM + d0]; a1 += aw * nbr_s[k * DIM + d1];
    }
    agg[(size_t)bn * DIM + d0] = a0; agg[(size_t)bn * DIM + d1] = a1;
}

__global__ __launch_bounds__(256) void out_gemm_fb(
    const float* __restrict__ selfv, const float* __restrict__ agg,
    const float* __restrict__ w3, float* __restrict__ out)
{
    __shared__ float in_lds[64][256];
    const int row0 = blockIdx.x * 64, tid = threadIdx.x;
    for (int idx = tid; idx < 64 * 64; idx += 256) {
        const int r = idx >> 6, c4 = idx & 63;
        float4 v;
        if (c4 < 32) v = ((const float4*)(selfv + (size_t)(row0 + r) * DIM))[c4];
        else         v = ((const float4*)(agg + (size_t)(row0 + r) * DIM))[c4 - 32];
        ((float4*)in_lds[r])[c4] = v;
    }
    __syncthreads();
    const int d0 = tid & 63, rbase = (tid >> 6) * 16;
    float acc0[16], acc1[16];
    #pragma unroll
    for (int r = 0; r < 16; ++r) { acc0[r] = 0.f; acc1[r] = 0.f; }
    for (int f = 0; f < 256; f += 4) {
        float w3a[4], w3b[4];
        #pragma unroll
        for (int j = 0; j < 4; ++j) {
            w3a[j] = w3[(f + j) * DIM + d0]; w3b[j] = w3[(f + j) * DIM + d0 + 64];
        }
        #pragma unroll
        for (int r = 0; r < 16; ++r) {
            float4 iv = *(const float4*)(&in_lds[rbase + r][f]);
            acc0[r] += iv.x * w3a[0] + iv.y * w3a[1] + iv.z * w3a[2] + iv.w * w3a[3];
            acc1[r] += iv.x * w3b[0] + iv.y * w3b[1] + iv.z * w3b[2] + iv.w * w3b[3];
        }
    }
    #pragma unroll
    for (int r = 0; r < 16; ++r) {
        const size_t row = (size_t)(row0 + rbase + r);
        out[row * DIM + d0] = fmaxf(acc0[r], 0.f);
        out[row * DIM + d0 + 64] = fmaxf(acc1[r], 0.f);
    }
}

// ---------------------------------------------------------------------------
extern "C" void kernel_launch(void* const* d_in, const int* in_sizes, int n_in,
                              void* d_out, int out_size, void* d_ws, size_t ws_size,
                              hipStream_t stream) {
    const float* selfv    = (const float*)d_in[0];
    const float* neighbor = (const float*)d_in[1];
    const float* nw       = (const float*)d_in[4];
    const float* extra    = (const float*)d_in[5];
    const float* w1       = (const float*)d_in[6];
    const float* w2       = (const float*)d_in[7];
    const float* w3       = (const float*)d_in[8];
    float* out = (float*)d_out;

    // ws layout: [0,32K) w1f bf16 | [32K,96K) w3f bf16 | [128K, 128K+8M) agg bf16
    const size_t need = (size_t)128 * 1024 + (size_t)BN * DIM * sizeof(unsigned short);
    if (ws_size >= need) {
        unsigned short* w1f  = (unsigned short*)d_ws;
        unsigned short* w3f  = (unsigned short*)((char*)d_ws + 32 * 1024);
        unsigned short* aggb = (unsigned short*)((char*)d_ws + 128 * 1024);
        prep_kernel<<<128, 256, 0, stream>>>(w1, w3, w1f, w3f);
        attn_mfma_kernel<<<BN / T1, 256, 0, stream>>>(neighbor, nw, extra, w1, w2, w1f, aggb);
        out_mfma_kernel<<<BN / 64, 256, 0, stream>>>(selfv, aggb, w3f, out);
    } else {
        // fp32 fallback (agg in-place through out is safe: tile fully staged first)
        attn_agg_fb<<<BN / 2, 128, 0, stream>>>(neighbor, nw, extra, w1, w2, out);
        out_gemm_fb<<<BN / 64, 256, 0, stream>>>(selfv, out, w3, out);
    }
}